// Round 3
// baseline (936.498 us; speedup 1.0000x reference)
//
#include <hip/hip_runtime.h>
#include <cstdint>
#include <cstddef>

#define T_TOK 4096
#define DIM   1024
#define NEXP  8
#define HDIM  4096

#define BM 128
#define BN 128
#define BK 32

typedef __attribute__((ext_vector_type(8))) short s16x8;
typedef __attribute__((ext_vector_type(4))) float f32x4;

__device__ __forceinline__ unsigned short f2bf(float f) {
    union { float f; unsigned u; } v; v.f = f;
    unsigned u = v.u;
    unsigned r = (u + 0x7FFFu + ((u >> 16) & 1u)) >> 16;  // RNE
    return (unsigned short)r;
}

// element offset into a [row][32] bf16 tile, 16B-chunk XOR swizzle:
// chunk' = chunk ^ ((row>>1)&3)  -> rows 0..7 cover all four 16B slots
__device__ __forceinline__ int lds_off(int row, int kchunk) {
    return row * 32 + ((kchunk ^ ((row >> 1) & 3)) << 3);
}

// ---------------- gating: fp32 logits, top-2, renormalized softmax ----------
__global__ __launch_bounds__(256) void gate_kernel(
    const float* __restrict__ x, const float* __restrict__ wg,
    int* __restrict__ tok_e, float* __restrict__ tok_w, int* __restrict__ counts)
{
    int t = blockIdx.x * 4 + (threadIdx.x >> 6);
    int lane = threadIdx.x & 63;
    float acc[NEXP];
#pragma unroll
    for (int e = 0; e < NEXP; ++e) acc[e] = 0.f;
    const float* xrow = x + (size_t)t * DIM;
    for (int d = lane; d < DIM; d += 64) {
        float xv = xrow[d];
        const float4* wr = (const float4*)(wg + (size_t)d * NEXP);
        float4 w0 = wr[0], w1v = wr[1];
        acc[0] += xv * w0.x;  acc[1] += xv * w0.y;
        acc[2] += xv * w0.z;  acc[3] += xv * w0.w;
        acc[4] += xv * w1v.x; acc[5] += xv * w1v.y;
        acc[6] += xv * w1v.z; acc[7] += xv * w1v.w;
    }
#pragma unroll
    for (int e = 0; e < NEXP; ++e)
#pragma unroll
        for (int off = 32; off > 0; off >>= 1)
            acc[e] += __shfl_xor(acc[e], off);
    if (lane == 0) {
        int i0 = 0;
#pragma unroll
        for (int e = 1; e < NEXP; ++e) if (acc[e] > acc[i0]) i0 = e;
        int i1 = (i0 == 0) ? 1 : 0;
#pragma unroll
        for (int e = 0; e < NEXP; ++e) if (e != i0 && acc[e] > acc[i1]) i1 = e;
        float w0 = 1.f / (1.f + __expf(acc[i1] - acc[i0]));
        tok_e[2 * t] = i0;  tok_e[2 * t + 1] = i1;
        tok_w[2 * t] = w0;  tok_w[2 * t + 1] = 1.f - w0;
        atomicAdd(&counts[i0], 1);
        atomicAdd(&counts[i1], 1);
    }
}

__global__ void scan_kernel(const int* __restrict__ counts,
                            int* __restrict__ offsets, int* __restrict__ cursor)
{
    if (threadIdx.x == 0) {
        int s = 0;
        for (int e = 0; e < NEXP; ++e) { offsets[e] = s; s += counts[e]; cursor[e] = 0; }
        offsets[NEXP] = s;
    }
}

__global__ __launch_bounds__(256) void assign_kernel(
    const int* __restrict__ tok_e, const float* __restrict__ tok_w,
    const int* __restrict__ offsets, int* __restrict__ cursor,
    int* __restrict__ rows_tok, float* __restrict__ rows_gate)
{
    int t = blockIdx.x * 256 + threadIdx.x;
    if (t >= T_TOK) return;
#pragma unroll
    for (int j = 0; j < 2; ++j) {
        int e = tok_e[2 * t + j];
        int pos = offsets[e] + atomicAdd(&cursor[e], 1);
        rows_tok[pos] = t;
        rows_gate[pos] = tok_w[2 * t + j];
    }
}

// ------------- transpose+convert: src [E][R][C] f32 -> dst [E][C][R] bf16 ---
// grid (C/64, R/128, E), block 256. Loads coalesced along C; each thread
// writes 64B contiguous along the dst row.
__global__ __launch_bounds__(256) void tconv_kernel(
    const float* __restrict__ src, unsigned short* __restrict__ dst, int R, int C)
{
    int e = blockIdx.z;
    int lane = threadIdx.x & 63;
    int w = threadIdx.x >> 6;
    int c = blockIdx.x * 64 + lane;
    int r0 = blockIdx.y * 128 + w * 32;
    const float* s = src + (size_t)e * R * C + (size_t)r0 * C + c;
    unsigned short* d = dst + (size_t)e * C * R + (size_t)c * R + r0;
#pragma unroll
    for (int jc = 0; jc < 4; ++jc) {
        s16x8 v;
#pragma unroll
        for (int j = 0; j < 8; ++j) v[j] = (short)f2bf(s[(size_t)(jc * 8 + j) * C]);
        *(s16x8*)(d + jc * 8) = v;
    }
}

// ---------------- GEMM1: h = silu(x@w1) * (x@w3), grouped by expert --------
// A: gathered token rows of x (fp32 -> bf16 on stage). B: w1t/w3t bf16 [H][D].
__global__ __launch_bounds__(256, 2) void gemm1_kernel(
    const float* __restrict__ x,
    const unsigned short* __restrict__ w1t, const unsigned short* __restrict__ w3t,
    const int* __restrict__ rows_tok, const int* __restrict__ offsets,
    unsigned short* __restrict__ h)
{
    int e = blockIdx.z;
    int offs = offsets[e];
    int cnt  = offsets[e + 1] - offs;
    int m0 = blockIdx.y * BM;
    if (m0 >= cnt) return;
    int n0 = blockIdx.x * BN;

    __shared__ unsigned short As[2][BM * BK];
    __shared__ unsigned short B1s[2][BN * BK];
    __shared__ unsigned short B3s[2][BN * BK];
    __shared__ int toks[BM];

    int tid = threadIdx.x;
    if (tid < BM) toks[tid] = rows_tok[offs + min(m0 + tid, cnt - 1)];
    __syncthreads();

    int lane = tid & 63;
    int wid = tid >> 6;
    int wr = wid >> 1, wc = wid & 1;
    int lr = lane & 15, lg = lane >> 4;

    int r2 = tid >> 1;          // staging row 0..127
    int halfsel = tid & 1;      // 16-element half of the 32-wide k slice
    int ch = halfsel * 2;
    const float* abase = x + (size_t)toks[r2] * DIM + halfsel * 16;
    const unsigned short* b1base = w1t + ((size_t)e * HDIM + n0 + r2) * DIM + halfsel * 16;
    const unsigned short* b3base = w3t + ((size_t)e * HDIM + n0 + r2) * DIM + halfsel * 16;

    f32x4 acc1[4][4] = {};
    f32x4 acc3[4][4] = {};

    auto stage = [&](int buf, int k0) {
        const float4* s4 = (const float4*)(abase + k0);
        float4 f0 = s4[0], f1 = s4[1], f2 = s4[2], f3 = s4[3];
        s16x8 bA0 = *(const s16x8*)(b1base + k0);
        s16x8 bA1 = *(const s16x8*)(b1base + k0 + 8);
        s16x8 bB0 = *(const s16x8*)(b3base + k0);
        s16x8 bB1 = *(const s16x8*)(b3base + k0 + 8);
        float fl[16] = { f0.x, f0.y, f0.z, f0.w, f1.x, f1.y, f1.z, f1.w,
                         f2.x, f2.y, f2.z, f2.w, f3.x, f3.y, f3.z, f3.w };
        s16x8 pa, pb;
#pragma unroll
        for (int j = 0; j < 8; ++j) {
            pa[j] = (short)f2bf(fl[j]);
            pb[j] = (short)f2bf(fl[8 + j]);
        }
        *(s16x8*)&As[buf][lds_off(r2, ch)]      = pa;
        *(s16x8*)&As[buf][lds_off(r2, ch + 1)]  = pb;
        *(s16x8*)&B1s[buf][lds_off(r2, ch)]     = bA0;
        *(s16x8*)&B1s[buf][lds_off(r2, ch + 1)] = bA1;
        *(s16x8*)&B3s[buf][lds_off(r2, ch)]     = bB0;
        *(s16x8*)&B3s[buf][lds_off(r2, ch + 1)] = bB1;
    };

    auto compute = [&](int buf) {
        s16x8 a[4];
#pragma unroll
        for (int m = 0; m < 4; ++m) {
            int row = wr * 64 + m * 16 + lr;
            a[m] = *(const s16x8*)&As[buf][lds_off(row, lg)];
        }
#pragma unroll
        for (int n = 0; n < 4; ++n) {
            int rowb = wc * 64 + n * 16 + lr;
            s16x8 b1f = *(const s16x8*)&B1s[buf][lds_off(rowb, lg)];
            s16x8 b3f = *(const s16x8*)&B3s[buf][lds_off(rowb, lg)];
#pragma unroll
            for (int m = 0; m < 4; ++m)
                acc1[m][n] = __builtin_amdgcn_mfma_f32_16x16x32_bf16(a[m], b1f, acc1[m][n], 0, 0, 0);
#pragma unroll
            for (int m = 0; m < 4; ++m)
                acc3[m][n] = __builtin_amdgcn_mfma_f32_16x16x32_bf16(a[m], b3f, acc3[m][n], 0, 0, 0);
        }
    };

    stage(0, 0);
    __syncthreads();
    int buf = 0;
    for (int kt = 1; kt < DIM / BK; ++kt) {
        stage(buf ^ 1, kt * BK);
        compute(buf);
        __syncthreads();
        buf ^= 1;
    }
    compute(buf);

    // epilogue: silu(acc1)*acc3 -> bf16 h
#pragma unroll
    for (int m = 0; m < 4; ++m)
#pragma unroll
        for (int n = 0; n < 4; ++n)
#pragma unroll
            for (int r = 0; r < 4; ++r) {
                int row_local = wr * 64 + m * 16 + lg * 4 + r;
                if (m0 + row_local < cnt) {
                    int col_local = wc * 64 + n * 16 + lr;
                    float g1 = acc1[m][n][r];
                    float hv = (g1 / (1.f + __expf(-g1))) * acc3[m][n][r];
                    h[(size_t)(offs + m0 + row_local) * HDIM + n0 + col_local] = f2bf(hv);
                }
            }
}

// ---------------- GEMM2: out[tok] += gate * (h @ w2) -----------------------
__global__ __launch_bounds__(256, 2) void gemm2_kernel(
    const unsigned short* __restrict__ h, const unsigned short* __restrict__ w2t,
    const int* __restrict__ rows_tok, const float* __restrict__ rows_gate,
    const int* __restrict__ offsets, float* __restrict__ out)
{
    int e = blockIdx.z;
    int offs = offsets[e];
    int cnt  = offsets[e + 1] - offs;
    int m0 = blockIdx.y * BM;
    if (m0 >= cnt) return;
    int n0 = blockIdx.x * BN;   // over DIM

    __shared__ unsigned short As[2][BM * BK];
    __shared__ unsigned short Bs[2][BN * BK];

    int tid = threadIdx.x;
    int lane = tid & 63;
    int wid = tid >> 6;
    int wr = wid >> 1, wc = wid & 1;
    int lr = lane & 15, lg = lane >> 4;

    int r2 = tid >> 1;
    int halfsel = tid & 1;
    int ch = halfsel * 2;
    int apos = offs + min(m0 + r2, cnt - 1);
    const unsigned short* abase = h + (size_t)apos * HDIM + halfsel * 16;
    const unsigned short* bbase = w2t + ((size_t)e * DIM + n0 + r2) * HDIM + halfsel * 16;

    f32x4 acc[4][4] = {};

    auto stage = [&](int buf, int k0) {
        s16x8 a0 = *(const s16x8*)(abase + k0);
        s16x8 a1 = *(const s16x8*)(abase + k0 + 8);
        s16x8 b0 = *(const s16x8*)(bbase + k0);
        s16x8 b1 = *(const s16x8*)(bbase + k0 + 8);
        *(s16x8*)&As[buf][lds_off(r2, ch)]     = a0;
        *(s16x8*)&As[buf][lds_off(r2, ch + 1)] = a1;
        *(s16x8*)&Bs[buf][lds_off(r2, ch)]     = b0;
        *(s16x8*)&Bs[buf][lds_off(r2, ch + 1)] = b1;
    };

    auto compute = [&](int buf) {
        s16x8 a[4];
#pragma unroll
        for (int m = 0; m < 4; ++m) {
            int row = wr * 64 + m * 16 + lr;
            a[m] = *(const s16x8*)&As[buf][lds_off(row, lg)];
        }
#pragma unroll
        for (int n = 0; n < 4; ++n) {
            int rowb = wc * 64 + n * 16 + lr;
            s16x8 bf = *(const s16x8*)&Bs[buf][lds_off(rowb, lg)];
#pragma unroll
            for (int m = 0; m < 4; ++m)
                acc[m][n] = __builtin_amdgcn_mfma_f32_16x16x32_bf16(a[m], bf, acc[m][n], 0, 0, 0);
        }
    };

    stage(0, 0);
    __syncthreads();
    int buf = 0;
    for (int kt = 1; kt < HDIM / BK; ++kt) {
        stage(buf ^ 1, kt * BK);
        compute(buf);
        __syncthreads();
        buf ^= 1;
    }
    compute(buf);

#pragma unroll
    for (int m = 0; m < 4; ++m)
#pragma unroll
        for (int n = 0; n < 4; ++n)
#pragma unroll
            for (int r = 0; r < 4; ++r) {
                int row_local = wr * 64 + m * 16 + lg * 4 + r;
                if (m0 + row_local < cnt) {
                    int pos = offs + m0 + row_local;
                    int col_local = wc * 64 + n * 16 + lr;
                    float v = acc[m][n][r] * rows_gate[pos];
                    atomicAdd(&out[(size_t)rows_tok[pos] * DIM + n0 + col_local], v);
                }
            }
}

// ---------------------------------------------------------------------------
extern "C" void kernel_launch(void* const* d_in, const int* in_sizes, int n_in,
                              void* d_out, int out_size, void* d_ws, size_t ws_size,
                              hipStream_t stream)
{
    const float* x  = (const float*)d_in[0];
    const float* wg = (const float*)d_in[1];
    const float* w1 = (const float*)d_in[2];
    const float* w3 = (const float*)d_in[3];
    const float* w2 = (const float*)d_in[4];
    float* out = (float*)d_out;

    // Workspace layout (total ~192.3 MiB; small arrays FIRST so they are
    // always in-bounds; w2t aliases w1t's region since w1t is dead after
    // gemm1 and tconv(w2) is stream-ordered after gemm1):
    char* ws = (char*)d_ws;
    size_t off = 0;
    auto alloc = [&](size_t bytes) -> void* {
        void* p = ws + off;
        off = (off + bytes + 255) & ~(size_t)255;
        return p;
    };
    int*   rows_tok  = (int*)alloc((size_t)2 * T_TOK * 4);
    float* rows_gate = (float*)alloc((size_t)2 * T_TOK * 4);
    int*   tok_e     = (int*)alloc((size_t)2 * T_TOK * 4);
    float* tok_w     = (float*)alloc((size_t)2 * T_TOK * 4);
    int*   counts    = (int*)alloc(NEXP * 4);
    int*   offsets   = (int*)alloc((NEXP + 1) * 4);
    int*   cursor    = (int*)alloc(NEXP * 4);
    unsigned short* w1t  = (unsigned short*)alloc((size_t)NEXP * HDIM * DIM * 2); // 64 MiB
    unsigned short* w3t  = (unsigned short*)alloc((size_t)NEXP * HDIM * DIM * 2); // 64 MiB
    unsigned short* hbuf = (unsigned short*)alloc((size_t)2 * T_TOK * HDIM * 2);  // 64 MiB
    unsigned short* w2t  = w1t;  // alias: w1t dead after gemm1

    hipMemsetAsync(counts, 0, NEXP * 4, stream);
    hipMemsetAsync(out, 0, (size_t)out_size * sizeof(float), stream);

    gate_kernel<<<T_TOK / 4, 256, 0, stream>>>(x, wg, tok_e, tok_w, counts);
    scan_kernel<<<1, 64, 0, stream>>>(counts, offsets, cursor);
    assign_kernel<<<T_TOK / 256, 256, 0, stream>>>(tok_e, tok_w, offsets, cursor,
                                                   rows_tok, rows_gate);
    // w1,w3: [E][D][H] -> [E][H][D]
    tconv_kernel<<<dim3(HDIM / 64, DIM / 128, NEXP), 256, 0, stream>>>(w1, w1t, DIM, HDIM);
    tconv_kernel<<<dim3(HDIM / 64, DIM / 128, NEXP), 256, 0, stream>>>(w3, w3t, DIM, HDIM);

    gemm1_kernel<<<dim3(HDIM / BN, T_TOK / BM, NEXP), 256, 0, stream>>>(
        x, w1t, w3t, rows_tok, offsets, hbuf);

    // w2: [E][H][D_out] -> [E][D_out][H]  (into w1t's region, now dead)
    tconv_kernel<<<dim3(DIM / 64, HDIM / 128, NEXP), 256, 0, stream>>>(w2, w2t, HDIM, DIM);

    gemm2_kernel<<<dim3(DIM / BN, T_TOK / BM, NEXP), 256, 0, stream>>>(
        hbuf, w2t, rows_tok, rows_gate, offsets, out);
}

// Round 4
// 639.018 us; speedup vs baseline: 1.4655x; 1.4655x over previous
//
#include <hip/hip_runtime.h>
#include <cstdint>
#include <cstddef>

#define T_TOK 4096
#define DIM   1024
#define NEXP  8
#define HDIM  4096
#define NSLOT (2 * T_TOK)

#define BM 128
#define BN 128
#define BK 32

typedef __attribute__((ext_vector_type(8))) short s16x8;
typedef __attribute__((ext_vector_type(4))) float f32x4;

__device__ __forceinline__ unsigned short f2bf(float f) {
    union { float f; unsigned u; } v; v.f = f;
    unsigned u = v.u;
    unsigned r = (u + 0x7FFFu + ((u >> 16) & 1u)) >> 16;  // RNE
    return (unsigned short)r;
}

// element offset into a [row][32] bf16 tile, 16B-chunk XOR swizzle:
// slot c of row holds global chunk c ^ ((row>>1)&3)
__device__ __forceinline__ int lds_off(int row, int kchunk) {
    return row * 32 + ((kchunk ^ ((row >> 1) & 3)) << 3);
}

// async global->LDS, 16B per lane; LDS dest must be wave-uniform base.
__device__ __forceinline__ void gload16(const void* g, void* l) {
    __builtin_amdgcn_global_load_lds(
        (const __attribute__((address_space(1))) unsigned int*)g,
        (__attribute__((address_space(3))) unsigned int*)l, 16, 0, 0);
}

// ---------------- gating: fp32 logits, top-2, renormalized softmax ----------
__global__ __launch_bounds__(256) void gate_kernel(
    const float* __restrict__ x, const float* __restrict__ wg,
    int* __restrict__ tok_e, float* __restrict__ tok_w, int* __restrict__ counts)
{
    int t = blockIdx.x * 4 + (threadIdx.x >> 6);
    int lane = threadIdx.x & 63;
    float acc[NEXP];
#pragma unroll
    for (int e = 0; e < NEXP; ++e) acc[e] = 0.f;
    const float* xrow = x + (size_t)t * DIM;
    for (int d = lane; d < DIM; d += 64) {
        float xv = xrow[d];
        const float4* wr = (const float4*)(wg + (size_t)d * NEXP);
        float4 w0 = wr[0], w1v = wr[1];
        acc[0] += xv * w0.x;  acc[1] += xv * w0.y;
        acc[2] += xv * w0.z;  acc[3] += xv * w0.w;
        acc[4] += xv * w1v.x; acc[5] += xv * w1v.y;
        acc[6] += xv * w1v.z; acc[7] += xv * w1v.w;
    }
#pragma unroll
    for (int e = 0; e < NEXP; ++e)
#pragma unroll
        for (int off = 32; off > 0; off >>= 1)
            acc[e] += __shfl_xor(acc[e], off);
    if (lane == 0) {
        int i0 = 0;
#pragma unroll
        for (int e = 1; e < NEXP; ++e) if (acc[e] > acc[i0]) i0 = e;
        int i1 = (i0 == 0) ? 1 : 0;
#pragma unroll
        for (int e = 0; e < NEXP; ++e) if (e != i0 && acc[e] > acc[i1]) i1 = e;
        float w0 = 1.f / (1.f + __expf(acc[i1] - acc[i0]));
        tok_e[2 * t] = i0;  tok_e[2 * t + 1] = i1;
        tok_w[2 * t] = w0;  tok_w[2 * t + 1] = 1.f - w0;
        atomicAdd(&counts[i0], 1);
        atomicAdd(&counts[i1], 1);
    }
}

__global__ void scan_kernel(const int* __restrict__ counts,
                            int* __restrict__ offsets, int* __restrict__ cursor)
{
    if (threadIdx.x == 0) {
        int s = 0;
        for (int e = 0; e < NEXP; ++e) { offsets[e] = s; s += counts[e]; cursor[e] = 0; }
        offsets[NEXP] = s;
    }
}

__global__ __launch_bounds__(256) void assign_kernel(
    const int* __restrict__ tok_e,
    const int* __restrict__ offsets, int* __restrict__ cursor,
    int* __restrict__ rows_tok, int* __restrict__ slot_of)
{
    int t = blockIdx.x * 256 + threadIdx.x;
    if (t >= T_TOK) return;
#pragma unroll
    for (int j = 0; j < 2; ++j) {
        int e = tok_e[2 * t + j];
        int pos = offsets[e] + atomicAdd(&cursor[e], 1);
        rows_tok[pos] = t;
        slot_of[2 * t + j] = pos;
    }
}

// ------- xconv: gather token rows into slot order, convert to bf16 ---------
__global__ __launch_bounds__(256) void xconv_kernel(
    const float* __restrict__ x, const int* __restrict__ rows_tok,
    unsigned short* __restrict__ xg)
{
    int slot = blockIdx.x;
    int tok = rows_tok[slot];
    int d = threadIdx.x * 4;
    float4 v = *(const float4*)(x + (size_t)tok * DIM + d);
    ushort4 o;
    o.x = f2bf(v.x); o.y = f2bf(v.y); o.z = f2bf(v.z); o.w = f2bf(v.w);
    *(ushort4*)(xg + (size_t)slot * DIM + d) = o;
}

// ------------- transpose+convert: src [E][R][C] f32 -> dst [E][C][R] bf16 ---
// 64x64 tile via LDS ([64c][33] u32 pad layout, <=2-way conflicts).
// Reads coalesced along C; writes 128B-contiguous segments along dst rows.
__global__ __launch_bounds__(256) void tconv_kernel(
    const float* __restrict__ src, unsigned short* __restrict__ dst, int R, int C)
{
    __shared__ unsigned int t_lds[64 * 33];
    int e = blockIdx.z;
    int c0 = blockIdx.x * 64, r0 = blockIdx.y * 64;
    int t = threadIdx.x;
    int lane = t & 63, w = t >> 6;
    const float* s = src + (size_t)e * R * C + (size_t)(r0 + w * 16) * C + c0 + lane;
#pragma unroll
    for (int j = 0; j < 8; ++j) {
        float v0 = s[(size_t)(2 * j) * C];
        float v1 = s[(size_t)(2 * j + 1) * C];
        unsigned int pk = (unsigned int)f2bf(v0) | ((unsigned int)f2bf(v1) << 16);
        t_lds[lane * 33 + (w * 8 + j)] = pk;   // pair p = rows (2p,2p+1) at col lane
    }
    __syncthreads();
    unsigned short* dbase = dst + (size_t)e * C * R;
#pragma unroll
    for (int rep = 0; rep < 2; ++rep) {
        int idx = rep * 256 + t;
        int c = idx >> 3, chunk = idx & 7;
        uint4 o;
        o.x = t_lds[c * 33 + chunk * 4 + 0];
        o.y = t_lds[c * 33 + chunk * 4 + 1];
        o.z = t_lds[c * 33 + chunk * 4 + 2];
        o.w = t_lds[c * 33 + chunk * 4 + 3];
        *(uint4*)(dbase + (size_t)(c0 + c) * R + r0 + chunk * 8) = o;
    }
}

// ---------------- GEMM1: h = silu(xg@w1) * (xg@w3), grouped by expert ------
// All-bf16 inputs; staging via global_load_lds (linear LDS dest, pre-swizzled
// global source chunk g = (lane&3) ^ ((row>>1)&3) matching lds_off reads).
__global__ __launch_bounds__(256, 2) void gemm1_kernel(
    const unsigned short* __restrict__ xg,
    const unsigned short* __restrict__ w1t, const unsigned short* __restrict__ w3t,
    const int* __restrict__ offsets, unsigned short* __restrict__ h)
{
    int e = blockIdx.z;
    int offs = offsets[e];
    int cnt  = offsets[e + 1] - offs;
    int m0 = blockIdx.y * BM;
    if (m0 >= cnt) return;
    int n0 = blockIdx.x * BN;

    __shared__ unsigned short As[2][BM * BK];
    __shared__ unsigned short B1s[2][BN * BK];
    __shared__ unsigned short B3s[2][BN * BK];

    int tid = threadIdx.x;
    int lane = tid & 63;
    int w = tid >> 6;
    int wr = w >> 1, wc = w & 1;
    int lr = lane & 15, lg = lane >> 4;

    const unsigned short* asrc[2];
    const unsigned short* b1src[2];
    const unsigned short* b3src[2];
#pragma unroll
    for (int i = 0; i < 2; ++i) {
        int seg = w * 2 + i;
        int row = seg * 16 + (lane >> 2);
        int g = (lane & 3) ^ ((row >> 1) & 3);
        int arow = offs + min(m0 + row, cnt - 1);
        asrc[i]  = xg  + (size_t)arow * DIM + g * 8;
        int brow = n0 + row;
        b1src[i] = w1t + ((size_t)e * HDIM + brow) * DIM + g * 8;
        b3src[i] = w3t + ((size_t)e * HDIM + brow) * DIM + g * 8;
    }

    f32x4 acc1[4][4] = {};
    f32x4 acc3[4][4] = {};

    auto stage = [&](int buf, int k0) {
#pragma unroll
        for (int i = 0; i < 2; ++i) {
            int seg = w * 2 + i;
            gload16(asrc[i] + k0,  &As[buf][seg * 512]);
            gload16(b1src[i] + k0, &B1s[buf][seg * 512]);
            gload16(b3src[i] + k0, &B3s[buf][seg * 512]);
        }
    };

    auto compute = [&](int buf) {
        s16x8 a[4];
#pragma unroll
        for (int m = 0; m < 4; ++m) {
            int row = wr * 64 + m * 16 + lr;
            a[m] = *(const s16x8*)&As[buf][lds_off(row, lg)];
        }
#pragma unroll
        for (int n = 0; n < 4; ++n) {
            int rowb = wc * 64 + n * 16 + lr;
            s16x8 b1f = *(const s16x8*)&B1s[buf][lds_off(rowb, lg)];
            s16x8 b3f = *(const s16x8*)&B3s[buf][lds_off(rowb, lg)];
#pragma unroll
            for (int m = 0; m < 4; ++m)
                acc1[m][n] = __builtin_amdgcn_mfma_f32_16x16x32_bf16(a[m], b1f, acc1[m][n], 0, 0, 0);
#pragma unroll
            for (int m = 0; m < 4; ++m)
                acc3[m][n] = __builtin_amdgcn_mfma_f32_16x16x32_bf16(a[m], b3f, acc3[m][n], 0, 0, 0);
        }
    };

    stage(0, 0);
    __syncthreads();
    int buf = 0;
    for (int kt = 1; kt < DIM / BK; ++kt) {
        stage(buf ^ 1, kt * BK);
        compute(buf);
        __syncthreads();
        buf ^= 1;
    }
    compute(buf);

#pragma unroll
    for (int m = 0; m < 4; ++m)
#pragma unroll
        for (int n = 0; n < 4; ++n)
#pragma unroll
            for (int r = 0; r < 4; ++r) {
                int row_local = wr * 64 + m * 16 + lg * 4 + r;
                if (m0 + row_local < cnt) {
                    int col_local = wc * 64 + n * 16 + lr;
                    float g1 = acc1[m][n][r];
                    float hv = (g1 / (1.f + __expf(-g1))) * acc3[m][n][r];
                    h[(size_t)(offs + m0 + row_local) * HDIM + n0 + col_local] = f2bf(hv);
                }
            }
}

// ---------------- GEMM2: outg[slot] = h @ w2 (per-slot, no atomics) --------
__global__ __launch_bounds__(256, 2) void gemm2_kernel(
    const unsigned short* __restrict__ h, const unsigned short* __restrict__ w2t,
    const int* __restrict__ offsets, float* __restrict__ outg)
{
    int e = blockIdx.z;
    int offs = offsets[e];
    int cnt  = offsets[e + 1] - offs;
    int m0 = blockIdx.y * BM;
    if (m0 >= cnt) return;
    int n0 = blockIdx.x * BN;   // over DIM

    __shared__ unsigned short As[2][BM * BK];
    __shared__ unsigned short Bs[2][BN * BK];

    int tid = threadIdx.x;
    int lane = tid & 63;
    int w = tid >> 6;
    int wr = w >> 1, wc = w & 1;
    int lr = lane & 15, lg = lane >> 4;

    const unsigned short* asrc[2];
    const unsigned short* bsrc[2];
#pragma unroll
    for (int i = 0; i < 2; ++i) {
        int seg = w * 2 + i;
        int row = seg * 16 + (lane >> 2);
        int g = (lane & 3) ^ ((row >> 1) & 3);
        int arow = offs + min(m0 + row, cnt - 1);
        asrc[i] = h   + (size_t)arow * HDIM + g * 8;
        bsrc[i] = w2t + ((size_t)e * DIM + n0 + row) * HDIM + g * 8;
    }

    f32x4 acc[4][4] = {};

    auto stage = [&](int buf, int k0) {
#pragma unroll
        for (int i = 0; i < 2; ++i) {
            int seg = w * 2 + i;
            gload16(asrc[i] + k0, &As[buf][seg * 512]);
            gload16(bsrc[i] + k0, &Bs[buf][seg * 512]);
        }
    };

    auto compute = [&](int buf) {
        s16x8 a[4];
#pragma unroll
        for (int m = 0; m < 4; ++m) {
            int row = wr * 64 + m * 16 + lr;
            a[m] = *(const s16x8*)&As[buf][lds_off(row, lg)];
        }
#pragma unroll
        for (int n = 0; n < 4; ++n) {
            int rowb = wc * 64 + n * 16 + lr;
            s16x8 bf = *(const s16x8*)&Bs[buf][lds_off(rowb, lg)];
#pragma unroll
            for (int m = 0; m < 4; ++m)
                acc[m][n] = __builtin_amdgcn_mfma_f32_16x16x32_bf16(a[m], bf, acc[m][n], 0, 0, 0);
        }
    };

    stage(0, 0);
    __syncthreads();
    int buf = 0;
    for (int kt = 1; kt < HDIM / BK; ++kt) {
        stage(buf ^ 1, kt * BK);
        compute(buf);
        __syncthreads();
        buf ^= 1;
    }
    compute(buf);

#pragma unroll
    for (int m = 0; m < 4; ++m)
#pragma unroll
        for (int n = 0; n < 4; ++n)
#pragma unroll
            for (int r = 0; r < 4; ++r) {
                int row_local = wr * 64 + m * 16 + lg * 4 + r;
                if (m0 + row_local < cnt) {
                    int col_local = wc * 64 + n * 16 + lr;
                    outg[(size_t)(offs + m0 + row_local) * DIM + n0 + col_local] = acc[m][n][r];
                }
            }
}

// ---------- combine: out[t] = g0*outg[slot0] + g1*outg[slot1] --------------
__global__ __launch_bounds__(256) void combine_kernel(
    const float* __restrict__ outg, const int* __restrict__ slot_of,
    const float* __restrict__ tok_w, float* __restrict__ out)
{
    int t = blockIdx.x;
    int s0 = slot_of[2 * t], s1 = slot_of[2 * t + 1];
    float g0 = tok_w[2 * t], g1 = tok_w[2 * t + 1];
    int d = threadIdx.x * 4;
    float4 a = *(const float4*)(outg + (size_t)s0 * DIM + d);
    float4 b = *(const float4*)(outg + (size_t)s1 * DIM + d);
    float4 o;
    o.x = g0 * a.x + g1 * b.x;
    o.y = g0 * a.y + g1 * b.y;
    o.z = g0 * a.z + g1 * b.z;
    o.w = g0 * a.w + g1 * b.w;
    *(float4*)(out + (size_t)t * DIM + d) = o;
}

// ---------------------------------------------------------------------------
extern "C" void kernel_launch(void* const* d_in, const int* in_sizes, int n_in,
                              void* d_out, int out_size, void* d_ws, size_t ws_size,
                              hipStream_t stream)
{
    const float* x  = (const float*)d_in[0];
    const float* wg = (const float*)d_in[1];
    const float* w1 = (const float*)d_in[2];
    const float* w3 = (const float*)d_in[3];
    const float* w2 = (const float*)d_in[4];
    float* out = (float*)d_out;

    // Workspace ~208.2 MiB. Aliases: w2t<-w1t (w1t dead after gemm1),
    // outg<-w3t (w3t dead after gemm1; outg 32MiB fits in 64MiB region).
    char* ws = (char*)d_ws;
    size_t off = 0;
    auto alloc = [&](size_t bytes) -> void* {
        void* p = ws + off;
        off = (off + bytes + 255) & ~(size_t)255;
        return p;
    };
    int*   rows_tok = (int*)alloc((size_t)NSLOT * 4);
    int*   slot_of  = (int*)alloc((size_t)NSLOT * 4);
    int*   tok_e    = (int*)alloc((size_t)NSLOT * 4);
    float* tok_w    = (float*)alloc((size_t)NSLOT * 4);
    int*   counts   = (int*)alloc(NEXP * 4);
    int*   offsets  = (int*)alloc((NEXP + 1) * 4);
    int*   cursor   = (int*)alloc(NEXP * 4);
    unsigned short* xg   = (unsigned short*)alloc((size_t)NSLOT * DIM * 2);       // 16 MiB
    unsigned short* w1t  = (unsigned short*)alloc((size_t)NEXP * HDIM * DIM * 2); // 64 MiB
    unsigned short* w3t  = (unsigned short*)alloc((size_t)NEXP * HDIM * DIM * 2); // 64 MiB
    unsigned short* hbuf = (unsigned short*)alloc((size_t)NSLOT * HDIM * 2);      // 64 MiB
    unsigned short* w2t  = w1t;           // alias: dead after gemm1
    float*          outg = (float*)w3t;   // alias: dead after gemm1

    hipMemsetAsync(counts, 0, NEXP * 4, stream);

    gate_kernel<<<T_TOK / 4, 256, 0, stream>>>(x, wg, tok_e, tok_w, counts);
    scan_kernel<<<1, 64, 0, stream>>>(counts, offsets, cursor);
    assign_kernel<<<T_TOK / 256, 256, 0, stream>>>(tok_e, offsets, cursor,
                                                   rows_tok, slot_of);
    xconv_kernel<<<NSLOT, 256, 0, stream>>>(x, rows_tok, xg);

    // w1,w3: [E][D][H] -> [E][H][D]
    tconv_kernel<<<dim3(HDIM / 64, DIM / 64, NEXP), 256, 0, stream>>>(w1, w1t, DIM, HDIM);
    tconv_kernel<<<dim3(HDIM / 64, DIM / 64, NEXP), 256, 0, stream>>>(w3, w3t, DIM, HDIM);

    gemm1_kernel<<<dim3(HDIM / BN, T_TOK / BM, NEXP), 256, 0, stream>>>(
        xg, w1t, w3t, offsets, hbuf);

    // w2: [E][H][D] -> [E][D][H]  (into w1t's region, now dead)
    tconv_kernel<<<dim3(DIM / 64, HDIM / 64, NEXP), 256, 0, stream>>>(w2, w2t, HDIM, DIM);

    gemm2_kernel<<<dim3(DIM / BN, T_TOK / BM, NEXP), 256, 0, stream>>>(
        hbuf, w2t, offsets, outg);

    combine_kernel<<<T_TOK, 256, 0, stream>>>(outg, slot_of, tok_w, out);
}

// Round 5
// 576.624 us; speedup vs baseline: 1.6241x; 1.1082x over previous
//
#include <hip/hip_runtime.h>
#include <cstdint>
#include <cstddef>

#define T_TOK 4096
#define DIM   1024
#define NEXP  8
#define HDIM  4096
#define NSLOT (2 * T_TOK)

#define BM 128
#define BN 128
#define BK 32

typedef __attribute__((ext_vector_type(8))) short s16x8;
typedef __attribute__((ext_vector_type(4))) float f32x4;

__device__ __forceinline__ unsigned short f2bf(float f) {
    union { float f; unsigned u; } v; v.f = f;
    unsigned u = v.u;
    unsigned r = (u + 0x7FFFu + ((u >> 16) & 1u)) >> 16;  // RNE
    return (unsigned short)r;
}

// element offset into a [row][32] bf16 tile, 16B-chunk XOR swizzle:
// slot c of row holds global chunk c ^ ((row>>1)&3)
__device__ __forceinline__ int lds_off(int row, int kchunk) {
    return row * 32 + ((kchunk ^ ((row >> 1) & 3)) << 3);
}

// async global->LDS, 16B per lane; LDS dest must be wave-uniform base.
__device__ __forceinline__ void gload16(const void* g, void* l) {
    __builtin_amdgcn_global_load_lds(
        (const __attribute__((address_space(1))) unsigned int*)g,
        (__attribute__((address_space(3))) unsigned int*)l, 16, 0, 0);
}

// ---------------- gating: fp32 logits, top-2, renormalized softmax ----------
__global__ __launch_bounds__(256) void gate_kernel(
    const float* __restrict__ x, const float* __restrict__ wg,
    int* __restrict__ tok_e, float* __restrict__ tok_w, int* __restrict__ counts)
{
    int t = blockIdx.x * 4 + (threadIdx.x >> 6);
    int lane = threadIdx.x & 63;
    float acc[NEXP];
#pragma unroll
    for (int e = 0; e < NEXP; ++e) acc[e] = 0.f;
    const float* xrow = x + (size_t)t * DIM;
    for (int d = lane; d < DIM; d += 64) {
        float xv = xrow[d];
        const float4* wr = (const float4*)(wg + (size_t)d * NEXP);
        float4 w0 = wr[0], w1v = wr[1];
        acc[0] += xv * w0.x;  acc[1] += xv * w0.y;
        acc[2] += xv * w0.z;  acc[3] += xv * w0.w;
        acc[4] += xv * w1v.x; acc[5] += xv * w1v.y;
        acc[6] += xv * w1v.z; acc[7] += xv * w1v.w;
    }
#pragma unroll
    for (int e = 0; e < NEXP; ++e)
#pragma unroll
        for (int off = 32; off > 0; off >>= 1)
            acc[e] += __shfl_xor(acc[e], off);
    if (lane == 0) {
        int i0 = 0;
#pragma unroll
        for (int e = 1; e < NEXP; ++e) if (acc[e] > acc[i0]) i0 = e;
        int i1 = (i0 == 0) ? 1 : 0;
#pragma unroll
        for (int e = 0; e < NEXP; ++e) if (e != i0 && acc[e] > acc[i1]) i1 = e;
        float w0 = 1.f / (1.f + __expf(acc[i1] - acc[i0]));
        tok_e[2 * t] = i0;  tok_e[2 * t + 1] = i1;
        tok_w[2 * t] = w0;  tok_w[2 * t + 1] = 1.f - w0;
        atomicAdd(&counts[i0], 1);
        atomicAdd(&counts[i1], 1);
    }
}

__global__ void scan_kernel(const int* __restrict__ counts,
                            int* __restrict__ offsets, int* __restrict__ cursor)
{
    if (threadIdx.x == 0) {
        int s = 0;
        for (int e = 0; e < NEXP; ++e) { offsets[e] = s; s += counts[e]; cursor[e] = 0; }
        offsets[NEXP] = s;
    }
}

__global__ __launch_bounds__(256) void assign_kernel(
    const int* __restrict__ tok_e,
    const int* __restrict__ offsets, int* __restrict__ cursor,
    int* __restrict__ rows_tok, int* __restrict__ slot_of)
{
    int t = blockIdx.x * 256 + threadIdx.x;
    if (t >= T_TOK) return;
#pragma unroll
    for (int j = 0; j < 2; ++j) {
        int e = tok_e[2 * t + j];
        int pos = offsets[e] + atomicAdd(&cursor[e], 1);
        rows_tok[pos] = t;
        slot_of[2 * t + j] = pos;
    }
}

// ------- xconv: gather token rows into slot order, convert to bf16 ---------
__global__ __launch_bounds__(256) void xconv_kernel(
    const float* __restrict__ x, const int* __restrict__ rows_tok,
    unsigned short* __restrict__ xg)
{
    int slot = blockIdx.x;
    int tok = rows_tok[slot];
    int d = threadIdx.x * 4;
    float4 v = *(const float4*)(x + (size_t)tok * DIM + d);
    ushort4 o;
    o.x = f2bf(v.x); o.y = f2bf(v.y); o.z = f2bf(v.z); o.w = f2bf(v.w);
    *(ushort4*)(xg + (size_t)slot * DIM + d) = o;
}

// ------------- transpose+convert: src [E][R][C] f32 -> dst [E][C][R] bf16 ---
// 64x64 tile via LDS ([64c][33] u32 pad layout, <=2-way conflicts).
__global__ __launch_bounds__(256) void tconv_kernel(
    const float* __restrict__ src, unsigned short* __restrict__ dst, int R, int C)
{
    __shared__ unsigned int t_lds[64 * 33];
    int e = blockIdx.z;
    int c0 = blockIdx.x * 64, r0 = blockIdx.y * 64;
    int t = threadIdx.x;
    int lane = t & 63, w = t >> 6;
    const float* s = src + (size_t)e * R * C + (size_t)(r0 + w * 16) * C + c0 + lane;
#pragma unroll
    for (int j = 0; j < 8; ++j) {
        float v0 = s[(size_t)(2 * j) * C];
        float v1 = s[(size_t)(2 * j + 1) * C];
        unsigned int pk = (unsigned int)f2bf(v0) | ((unsigned int)f2bf(v1) << 16);
        t_lds[lane * 33 + (w * 8 + j)] = pk;   // pair p = rows (2p,2p+1) at col lane
    }
    __syncthreads();
    unsigned short* dbase = dst + (size_t)e * C * R;
#pragma unroll
    for (int rep = 0; rep < 2; ++rep) {
        int idx = rep * 256 + t;
        int c = idx >> 3, chunk = idx & 7;
        uint4 o;
        o.x = t_lds[c * 33 + chunk * 4 + 0];
        o.y = t_lds[c * 33 + chunk * 4 + 1];
        o.z = t_lds[c * 33 + chunk * 4 + 2];
        o.w = t_lds[c * 33 + chunk * 4 + 3];
        *(uint4*)(dbase + (size_t)(c0 + c) * R + r0 + chunk * 8) = o;
    }
}

// ---------------- GEMM1: h = silu(xg@w1) * (xg@w3), grouped by expert ------
// 512 threads / 8 waves (2Mx4N), wave-tile 64x32 per B. Light per-thread
// state (acc 64 regs) -> 4 waves/SIMD, 2 blocks/CU.
__global__ __launch_bounds__(512, 4) void gemm1_kernel(
    const unsigned short* __restrict__ xg,
    const unsigned short* __restrict__ w1t, const unsigned short* __restrict__ w3t,
    const int* __restrict__ offsets, unsigned short* __restrict__ h)
{
    int e = blockIdx.z;
    int offs = offsets[e];
    int cnt  = offsets[e + 1] - offs;
    int m0 = blockIdx.y * BM;
    if (m0 >= cnt) return;
    int n0 = blockIdx.x * BN;

    __shared__ unsigned short As[2][BM * BK];
    __shared__ unsigned short B1s[2][BN * BK];
    __shared__ unsigned short B3s[2][BN * BK];

    int tid = threadIdx.x;
    int lane = tid & 63;
    int wid = tid >> 6;              // 0..7
    int wr = wid >> 2, wc = wid & 3; // 2M x 4N
    int lr = lane & 15, lg = lane >> 4;

    // staging: thread -> (row = tid>>2, chunk = tid&3), 1 gload16 per buffer
    int srow = tid >> 2;
    int g = (tid & 3) ^ ((srow >> 1) & 3);
    int arow = offs + min(m0 + srow, cnt - 1);
    const unsigned short* asrc  = xg  + (size_t)arow * DIM + g * 8;
    const unsigned short* b1src = w1t + ((size_t)e * HDIM + n0 + srow) * DIM + g * 8;
    const unsigned short* b3src = w3t + ((size_t)e * HDIM + n0 + srow) * DIM + g * 8;
    int ldsbase = wid * 512;   // wave-uniform: wave writes 1KB linear per buffer

    f32x4 acc1[4][2] = {};
    f32x4 acc3[4][2] = {};

    auto stage = [&](int buf, int k0) {
        gload16(asrc + k0,  &As[buf][ldsbase]);
        gload16(b1src + k0, &B1s[buf][ldsbase]);
        gload16(b3src + k0, &B3s[buf][ldsbase]);
    };

    auto compute = [&](int buf) {
        s16x8 a[4];
#pragma unroll
        for (int m = 0; m < 4; ++m)
            a[m] = *(const s16x8*)&As[buf][lds_off(wr * 64 + m * 16 + lr, lg)];
#pragma unroll
        for (int n = 0; n < 2; ++n) {
            int rowb = wc * 32 + n * 16 + lr;
            s16x8 b1f = *(const s16x8*)&B1s[buf][lds_off(rowb, lg)];
            s16x8 b3f = *(const s16x8*)&B3s[buf][lds_off(rowb, lg)];
#pragma unroll
            for (int m = 0; m < 4; ++m)
                acc1[m][n] = __builtin_amdgcn_mfma_f32_16x16x32_bf16(a[m], b1f, acc1[m][n], 0, 0, 0);
#pragma unroll
            for (int m = 0; m < 4; ++m)
                acc3[m][n] = __builtin_amdgcn_mfma_f32_16x16x32_bf16(a[m], b3f, acc3[m][n], 0, 0, 0);
        }
    };

    stage(0, 0);
    __syncthreads();
    int buf = 0;
    for (int kt = 1; kt < DIM / BK; ++kt) {
        stage(buf ^ 1, kt * BK);
        compute(buf);
        __syncthreads();
        buf ^= 1;
    }
    compute(buf);

#pragma unroll
    for (int m = 0; m < 4; ++m)
#pragma unroll
        for (int n = 0; n < 2; ++n)
#pragma unroll
            for (int r = 0; r < 4; ++r) {
                int row_local = wr * 64 + m * 16 + lg * 4 + r;
                if (m0 + row_local < cnt) {
                    int col_local = wc * 32 + n * 16 + lr;
                    float g1 = acc1[m][n][r];
                    float hv = (g1 / (1.f + __expf(-g1))) * acc3[m][n][r];
                    h[(size_t)(offs + m0 + row_local) * HDIM + n0 + col_local] = f2bf(hv);
                }
            }
}

// ---------------- GEMM2: outg[slot] = h @ w2 (per-slot, no atomics) --------
__global__ __launch_bounds__(512, 4) void gemm2_kernel(
    const unsigned short* __restrict__ h, const unsigned short* __restrict__ w2t,
    const int* __restrict__ offsets, float* __restrict__ outg)
{
    int e = blockIdx.z;
    int offs = offsets[e];
    int cnt  = offsets[e + 1] - offs;
    int m0 = blockIdx.y * BM;
    if (m0 >= cnt) return;
    int n0 = blockIdx.x * BN;   // over DIM

    __shared__ unsigned short As[2][BM * BK];
    __shared__ unsigned short Bs[2][BN * BK];

    int tid = threadIdx.x;
    int lane = tid & 63;
    int wid = tid >> 6;
    int wr = wid >> 2, wc = wid & 3;
    int lr = lane & 15, lg = lane >> 4;

    int srow = tid >> 2;
    int g = (tid & 3) ^ ((srow >> 1) & 3);
    int arow = offs + min(m0 + srow, cnt - 1);
    const unsigned short* asrc = h   + (size_t)arow * HDIM + g * 8;
    const unsigned short* bsrc = w2t + ((size_t)e * DIM + n0 + srow) * HDIM + g * 8;
    int ldsbase = wid * 512;

    f32x4 acc[4][2] = {};

    auto stage = [&](int buf, int k0) {
        gload16(asrc + k0, &As[buf][ldsbase]);
        gload16(bsrc + k0, &Bs[buf][ldsbase]);
    };

    auto compute = [&](int buf) {
        s16x8 a[4];
#pragma unroll
        for (int m = 0; m < 4; ++m)
            a[m] = *(const s16x8*)&As[buf][lds_off(wr * 64 + m * 16 + lr, lg)];
#pragma unroll
        for (int n = 0; n < 2; ++n) {
            s16x8 bf = *(const s16x8*)&Bs[buf][lds_off(wc * 32 + n * 16 + lr, lg)];
#pragma unroll
            for (int m = 0; m < 4; ++m)
                acc[m][n] = __builtin_amdgcn_mfma_f32_16x16x32_bf16(a[m], bf, acc[m][n], 0, 0, 0);
        }
    };

    stage(0, 0);
    __syncthreads();
    int buf = 0;
    for (int kt = 1; kt < HDIM / BK; ++kt) {
        stage(buf ^ 1, kt * BK);
        compute(buf);
        __syncthreads();
        buf ^= 1;
    }
    compute(buf);

#pragma unroll
    for (int m = 0; m < 4; ++m)
#pragma unroll
        for (int n = 0; n < 2; ++n)
#pragma unroll
            for (int r = 0; r < 4; ++r) {
                int row_local = wr * 64 + m * 16 + lg * 4 + r;
                if (m0 + row_local < cnt) {
                    int col_local = wc * 32 + n * 16 + lr;
                    outg[(size_t)(offs + m0 + row_local) * DIM + n0 + col_local] = acc[m][n][r];
                }
            }
}

// ---------- combine: out[t] = g0*outg[slot0] + g1*outg[slot1] --------------
__global__ __launch_bounds__(256) void combine_kernel(
    const float* __restrict__ outg, const int* __restrict__ slot_of,
    const float* __restrict__ tok_w, float* __restrict__ out)
{
    int t = blockIdx.x;
    int s0 = slot_of[2 * t], s1 = slot_of[2 * t + 1];
    float g0 = tok_w[2 * t], g1 = tok_w[2 * t + 1];
    int d = threadIdx.x * 4;
    float4 a = *(const float4*)(outg + (size_t)s0 * DIM + d);
    float4 b = *(const float4*)(outg + (size_t)s1 * DIM + d);
    float4 o;
    o.x = g0 * a.x + g1 * b.x;
    o.y = g0 * a.y + g1 * b.y;
    o.z = g0 * a.z + g1 * b.z;
    o.w = g0 * a.w + g1 * b.w;
    *(float4*)(out + (size_t)t * DIM + d) = o;
}

// ---------------------------------------------------------------------------
extern "C" void kernel_launch(void* const* d_in, const int* in_sizes, int n_in,
                              void* d_out, int out_size, void* d_ws, size_t ws_size,
                              hipStream_t stream)
{
    const float* x  = (const float*)d_in[0];
    const float* wg = (const float*)d_in[1];
    const float* w1 = (const float*)d_in[2];
    const float* w3 = (const float*)d_in[3];
    const float* w2 = (const float*)d_in[4];
    float* out = (float*)d_out;

    // Workspace ~208.2 MiB. Aliases: w2t<-w1t (w1t dead after gemm1),
    // outg<-w3t (w3t dead after gemm1; outg 32MiB fits in 64MiB region).
    char* ws = (char*)d_ws;
    size_t off = 0;
    auto alloc = [&](size_t bytes) -> void* {
        void* p = ws + off;
        off = (off + bytes + 255) & ~(size_t)255;
        return p;
    };
    int*   rows_tok = (int*)alloc((size_t)NSLOT * 4);
    int*   slot_of  = (int*)alloc((size_t)NSLOT * 4);
    int*   tok_e    = (int*)alloc((size_t)NSLOT * 4);
    float* tok_w    = (float*)alloc((size_t)NSLOT * 4);
    int*   counts   = (int*)alloc(NEXP * 4);
    int*   offsets  = (int*)alloc((NEXP + 1) * 4);
    int*   cursor   = (int*)alloc(NEXP * 4);
    unsigned short* xg   = (unsigned short*)alloc((size_t)NSLOT * DIM * 2);       // 16 MiB
    unsigned short* w1t  = (unsigned short*)alloc((size_t)NEXP * HDIM * DIM * 2); // 64 MiB
    unsigned short* w3t  = (unsigned short*)alloc((size_t)NEXP * HDIM * DIM * 2); // 64 MiB
    unsigned short* hbuf = (unsigned short*)alloc((size_t)NSLOT * HDIM * 2);      // 64 MiB
    unsigned short* w2t  = w1t;           // alias: dead after gemm1
    float*          outg = (float*)w3t;   // alias: dead after gemm1

    hipMemsetAsync(counts, 0, NEXP * 4, stream);

    gate_kernel<<<T_TOK / 4, 256, 0, stream>>>(x, wg, tok_e, tok_w, counts);
    scan_kernel<<<1, 64, 0, stream>>>(counts, offsets, cursor);
    assign_kernel<<<T_TOK / 256, 256, 0, stream>>>(tok_e, offsets, cursor,
                                                   rows_tok, slot_of);
    xconv_kernel<<<NSLOT, 256, 0, stream>>>(x, rows_tok, xg);

    // w1,w3: [E][D][H] -> [E][H][D]
    tconv_kernel<<<dim3(HDIM / 64, DIM / 64, NEXP), 256, 0, stream>>>(w1, w1t, DIM, HDIM);
    tconv_kernel<<<dim3(HDIM / 64, DIM / 64, NEXP), 256, 0, stream>>>(w3, w3t, DIM, HDIM);

    gemm1_kernel<<<dim3(HDIM / BN, T_TOK / BM, NEXP), 512, 0, stream>>>(
        xg, w1t, w3t, offsets, hbuf);

    // w2: [E][H][D] -> [E][D][H]  (into w1t's region, now dead)
    tconv_kernel<<<dim3(DIM / 64, HDIM / 64, NEXP), 256, 0, stream>>>(w2, w2t, HDIM, DIM);

    gemm2_kernel<<<dim3(DIM / BN, T_TOK / BM, NEXP), 512, 0, stream>>>(
        hbuf, w2t, offsets, outg);

    combine_kernel<<<T_TOK, 256, 0, stream>>>(outg, slot_of, tok_w, out);
}